// Round 7
// baseline (115.746 us; speedup 1.0000x reference)
//
#include <hip/hip_runtime.h>
#include <hip/hip_bf16.h>

// KPConv MI355X — Round 7: occupancy restructure (TP=16, 3 blocks/CU,
// 24 waves/CU) + provably conflict-free LDS layout + revert phase-B
// W-load amplification.
// B=2, N=16384, M=16384, K=32, C_IN=64, C_OUT=128, KS=15, sigma=0.05.
//
// LDS layout (16-B chunks): addr(pl, j, u) = j*2048 + u*256 + ((pl^(j&7))*16)
//   pl = point 0..15, j = kernel pt 0..15 (15 = pad), u = c-octet 0..7.
//   Phase-A b64 writes: depth-4/bank (floor). Phase-B b128 reads:
//   depth-8/bank (floor). Zero excess bank conflicts by construction.
// Phase A (wave = 2 points): influences in B-frag layout via sentinel pad,
//   DPP row_ror normalize, feats gathered as uint2 (permuted bf16 prepass),
//   one 16x16x32 MFMA per c-tile, D -> bf16 -> LDS.
// Phase B: wave wv = n-tile wv; 30 steps x (1 ds_read_b128 + 1 W b128 + 1 MFMA).

#define NB   16384
#define MB   16384
#define KN   32
#define CIN  64
#define COUT 128
#define KS   15
#define TP   16
#define WF_BYTES  245760u
#define FP_BYTES  (2u * MB * CIN * 2u)    // 4,194,304
#define SP4_BYTES (2u * MB * 16u)         //   524,288

typedef __attribute__((ext_vector_type(8))) short short8;
typedef __attribute__((ext_vector_type(4))) float f32x4;

// rotation-reduce step over the 16-lane DPP row: s += row_ror<n>(s)
#define ROR_ADD(s, ctrl) \
    ((s) + __int_as_float(__builtin_amdgcn_update_dpp( \
        0, __float_as_int(s), (ctrl), 0xF, 0xF, true)))

// bf16 pack (round-to-nearest, ties-away): low short = f0, high short = f1
static __device__ __forceinline__ unsigned int pack2_bf16(float f0, float f1) {
    const unsigned int a = __float_as_uint(f0) + 0x8000u;
    const unsigned int b = __float_as_uint(f1) + 0x8000u;
    return (a >> 16) | (b & 0xffff0000u);
}

static __device__ __forceinline__ unsigned int pack2_bf16_rne(float f0, float f1) {
    unsigned int a = __float_as_uint(f0);
    unsigned int b = __float_as_uint(f1);
    a += 0x7fffu + ((a >> 16) & 1u);
    b += 0x7fffu + ((b >> 16) & 1u);
    return (a >> 16) | (b & 0xffff0000u);
}

static __device__ __forceinline__ unsigned short f32_to_bf16_rne(float x) {
    unsigned int u = __float_as_uint(x);
    u += 0x7fffu + ((u >> 16) & 1u);
    return (unsigned short)(u >> 16);
}

__global__ __launch_bounds__(256)
void prep_kernel(const float* __restrict__ Wg, const float* __restrict__ feats,
                 const float* __restrict__ sp,
                 unsigned short* __restrict__ wf, unsigned int* __restrict__ fp,
                 float4* __restrict__ sp4, int full) {
    const int bid = blockIdx.x;
    if (bid < 60) {
        // W -> bf16 B-frag layout (15360 threads exactly)
        const int tid = bid * 256 + threadIdx.x;
        const int l = tid & 63;
        const int t = (tid >> 6) & 7;
        const int s = tid >> 9;
        const int n  = t * 16 + (l & 15);
        const int kb = s * 32 + (l >> 4) * 8;
        short8 o;
        #pragma unroll
        for (int i = 0; i < 8; ++i)
            o[i] = (short)f32_to_bf16_rne(Wg[(kb + i) * COUT + n]);
        *(short8*)(wf + (size_t)tid * 8) = o;
    } else if (!full) {
        return;
    } else if (bid < 60 + 128) {
        // support points -> float4 (32768 threads exactly)
        const int m = (bid - 60) * 256 + threadIdx.x;
        const float* s3 = sp + 3 * (size_t)m;
        sp4[m] = make_float4(s3[0], s3[1], s3[2], 0.0f);
    } else {
        // feats -> bf16 permuted: row m, position p=n16*4+t holds c=t*16+n16
        const unsigned int t = (unsigned int)(bid - 188) * 256u + threadIdx.x;
        if (t < 2u * MB * 32u) {          // u32 outputs: 32 per row
            const int m   = t >> 5;
            const int p2  = t & 31;       // output u32 = positions 2p2,2p2+1
            const int n16 = p2 >> 1;
            const int tt  = (p2 & 1) * 2;
            const float a = feats[(size_t)m * CIN + tt * 16 + n16];
            const float b = feats[(size_t)m * CIN + (tt + 1) * 16 + n16];
            fp[t] = pack2_bf16_rne(a, b);
        }
    }
}

template<bool PK>
__global__ __launch_bounds__(512, 6)
void kpconv_mfma(const float* __restrict__ qp,
                 const float* __restrict__ sp,
                 const float* __restrict__ feats,
                 const unsigned int* __restrict__ fpk,
                 const float4* __restrict__ sp4,
                 const int* __restrict__ nidx,
                 const float* __restrict__ kp,
                 const unsigned short* __restrict__ wfrag,
                 const float* __restrict__ bias,
                 float* __restrict__ out) {
    __shared__ __align__(16) char sF[16 * 2048];   // 32768 B -> 3+ blocks/CU

    const int tid  = threadIdx.x;
    const int lane = tid & 63;
    const int wv   = tid >> 6;                 // 0..7
    const int gp_base = blockIdx.x * TP;
    const int b = gp_base >> 14;
    const float*        fbf  = feats + (size_t)b * MB * CIN;
    const unsigned int* fpb  = fpk + (size_t)b * MB * 32;       // 32 u32/row
    const float4*       sp4b = sp4 + (size_t)b * MB;
    const float*        spb  = sp + (size_t)b * MB * 3;

    const int n16  = lane & 15;     // j (influence col) / c-sub / point-in-tile
    const int quad = lane >> 4;     // k-group selector

    // kernel point for this lane's j; j==15 pad -> sentinel far away so
    // exp(-200*d2) underflows to exactly 0 (no per-element mask needed)
    float kxj, kyj, kzj;
    if (n16 < 15) {
        kxj = kp[3 * n16 + 0];
        kyj = kp[3 * n16 + 1];
        kzj = kp[3 * n16 + 2];
    } else {
        kxj = 1.0e4f; kyj = 1.0e4f; kzj = 1.0e4f;
    }

    // ---------------- Phase A: 2 points per wave ----------------
    const int gp0 = gp_base + wv * 2;
    const int* ip = nidx + (size_t)gp0 * KN + quad * 8;

    // preload both points' neighbor indices
    int idx0[8], idx1[8];
    *(int4*)(&idx0[0]) = *(const int4*)(ip);
    *(int4*)(&idx0[4]) = *(const int4*)(ip + 4);
    *(int4*)(&idx1[0]) = *(const int4*)(ip + KN);
    *(int4*)(&idx1[4]) = *(const int4*)(ip + KN + 4);

    #pragma unroll
    for (int pt = 0; pt < 2; ++pt) {
        const int pl = wv * 2 + pt;
        const int gp = gp0 + pt;
        const int* idxv = pt ? idx1 : idx0;

        const float qx = qp[3 * gp + 0];
        const float qy = qp[3 * gp + 1];
        const float qz = qp[3 * gp + 2];
        const float qkx = qx + kxj, qky = qy + kyj, qkz = qz + kzj;

        float e[8];
        uint2 g[8];
        if (PK) {
            float4 s4[8];
            #pragma unroll
            for (int i = 0; i < 8; ++i) s4[i] = sp4b[idxv[i]];
            #pragma unroll
            for (int i = 0; i < 8; ++i)
                g[i] = *(const uint2*)(fpb + (size_t)idxv[i] * 32 + n16 * 2);
            #pragma unroll
            for (int i = 0; i < 8; ++i) {
                const float dx = s4[i].x - qkx;
                const float dy = s4[i].y - qky;
                const float dz = s4[i].z - qkz;
                const float d2 = fmaf(dx, dx, fmaf(dy, dy, dz * dz));
                e[i] = __expf(-200.0f * d2);   // 1/(2*sigma^2); j=15 -> 0
            }
        } else {
            #pragma unroll
            for (int i = 0; i < 8; ++i) {
                const float* s3 = spb + (size_t)idxv[i] * 3;
                const float dx = s3[0] - qkx;
                const float dy = s3[1] - qky;
                const float dz = s3[2] - qkz;
                const float d2 = fmaf(dx, dx, fmaf(dy, dy, dz * dz));
                e[i] = __expf(-200.0f * d2);
            }
        }

        // normalize over j = 16-lane DPP row, pure VALU rotation-reduce
        unsigned int iu[4];
        float en[8];
        #pragma unroll
        for (int i = 0; i < 8; ++i) {
            float s = e[i];
            s = ROR_ADD(s, 0x128);   // row_ror:8
            s = ROR_ADD(s, 0x124);   // row_ror:4
            s = ROR_ADD(s, 0x122);   // row_ror:2
            s = ROR_ADD(s, 0x121);   // row_ror:1
            en[i] = e[i] * __builtin_amdgcn_rcpf(s + 1e-6f);
        }
        #pragma unroll
        for (int ih = 0; ih < 4; ++ih)
            iu[ih] = pack2_bf16(en[2 * ih], en[2 * ih + 1]);
        const short8 ifrag = *(const short8*)iu;

        // feats A-frags: elem i = feat[idx[quad*8+i]][c=t*16+n16]
        unsigned int fu[4][4];
        if (PK) {
            #pragma unroll
            for (int ih = 0; ih < 4; ++ih) {
                const unsigned int ax = g[2 * ih].x, bx = g[2 * ih + 1].x;
                const unsigned int ay = g[2 * ih].y, by = g[2 * ih + 1].y;
                fu[0][ih] = __builtin_amdgcn_perm(bx, ax, 0x05040100u);
                fu[1][ih] = __builtin_amdgcn_perm(bx, ax, 0x07060302u);
                fu[2][ih] = __builtin_amdgcn_perm(by, ay, 0x05040100u);
                fu[3][ih] = __builtin_amdgcn_perm(by, ay, 0x07060302u);
            }
        } else {
            #pragma unroll
            for (int ih = 0; ih < 4; ++ih) {
                const float* fr0 = fbf + (size_t)idxv[2 * ih]     * CIN + n16;
                const float* fr1 = fbf + (size_t)idxv[2 * ih + 1] * CIN + n16;
                #pragma unroll
                for (int t = 0; t < 4; ++t)
                    fu[t][ih] = pack2_bf16(fr0[t * 16], fr1[t * 16]);
            }
        }

        // MFMA per c-tile t; D[c_local = quad*4+r][j = n16].
        // Store 4 bf16 (c = t*16+quad*4 .. +3) as one b64 to chunk
        // u = t*2 + (quad>>1), half (quad&1); row swizzle pl^(n16&7).
        #pragma unroll
        for (int t = 0; t < 4; ++t) {
            const short8 ffrag = *(const short8*)(fu[t]);
            f32x4 z = {0.f, 0.f, 0.f, 0.f};
            const f32x4 dd = __builtin_amdgcn_mfma_f32_16x16x32_bf16(ffrag, ifrag, z, 0, 0, 0);
            const unsigned int lo = pack2_bf16(dd[0], dd[1]);
            const unsigned int hi = pack2_bf16(dd[2], dd[3]);
            const int off = n16 * 2048 + (t * 2 + (quad >> 1)) * 256 +
                            ((pl ^ (n16 & 7)) * 16) + (quad & 1) * 8;
            uint2 v; v.x = lo; v.y = hi;
            *(uint2*)(sF + off) = v;                  // ds_write_b64
        }
    }
    __syncthreads();

    // ---- Phase B: wave wv = n-tile; 30 x (ds_read_b128 + W b128 + MFMA) ----
    f32x4 acc = {0.f, 0.f, 0.f, 0.f};

    #pragma unroll
    for (int s = 0; s < 30; ++s) {
        const int j = s >> 1;
        const int u = (s & 1) * 4 + quad;
        const int off = j * 2048 + u * 256 + ((n16 ^ (j & 7)) * 16);
        const short8 a  = *(const short8*)(sF + off);
        const short8 bf = *(const short8*)(wfrag + ((size_t)(s * 8 + wv) * 64 + lane) * 8);
        acc = __builtin_amdgcn_mfma_f32_16x16x32_bf16(a, bf, acc, 0, 0, 0);
    }

    const float bsv = bias[wv * 16 + n16];
    #pragma unroll
    for (int r = 0; r < 4; ++r) {
        out[(size_t)(gp_base + quad * 4 + r) * COUT + wv * 16 + n16] = acc[r] + bsv;
    }
}

extern "C" void kernel_launch(void* const* d_in, const int* in_sizes, int n_in,
                              void* d_out, int out_size, void* d_ws, size_t ws_size,
                              hipStream_t stream) {
    const float* qp = (const float*)d_in[0];   // query_points   [B,N,3]
    const float* sp = (const float*)d_in[1];   // support_points [B,M,3]
    const float* ft = (const float*)d_in[2];   // support_features [B,M,C_IN]
    const int*   ni = (const int*)d_in[3];     // neighbor_idx   [B,N,K]
    const float* kp = (const float*)d_in[4];   // kernel_points  [KS,3]
    const float* wg = (const float*)d_in[5];   // weights        [KS,C_IN,C_OUT]
    const float* bs = (const float*)d_in[6];   // bias           [C_OUT]
    float* o = (float*)d_out;                  // [B,N,C_OUT] fp32

    unsigned short* wfrag = (unsigned short*)d_ws;
    unsigned int*   fpk   = (unsigned int*)((char*)d_ws + WF_BYTES);
    float4*         sp4   = (float4*)((char*)d_ws + WF_BYTES + FP_BYTES);
    const int full = (ws_size >= (size_t)(WF_BYTES + FP_BYTES + SP4_BYTES)) ? 1 : 0;

    const int prep_blocks = full ? (60 + 128 + 4096) : 60;
    hipLaunchKernelGGL(prep_kernel, dim3(prep_blocks), dim3(256), 0, stream,
                       wg, ft, sp, wfrag, fpk, sp4, full);

    if (full) {
        hipLaunchKernelGGL((kpconv_mfma<true>), dim3((2 * NB) / TP), dim3(512), 0, stream,
                           qp, sp, ft, fpk, sp4, ni, kp, wfrag, bs, o);
    } else {
        hipLaunchKernelGGL((kpconv_mfma<false>), dim3((2 * NB) / TP), dim3(512), 0, stream,
                           qp, sp, ft, fpk, sp4, ni, kp, wfrag, bs, o);
    }
}

// Round 8
// 109.179 us; speedup vs baseline: 1.0601x; 1.0601x over previous
//
#include <hip/hip_runtime.h>
#include <hip/hip_bf16.h>

// KPConv MI355X — Round 8: R5 phase-B W-efficiency (251 MB L2) + R7
// conflict-free LDS layout + software-pipelined phase-A gathers.
// B=2, N=16384, M=16384, K=32, C_IN=64, C_OUT=128, KS=15, sigma=0.05.
//
// LDS (16-B chunks): addr(j, u, pl) = j*4096 + u*512 + ((pl^(j&7))*16)
//   j = kernel pt 0..15 (15 pad), u = c-octet 0..7, pl = point 0..31.
//   Phase-A b64 writes: depth-4/bank floor. Phase-B b128 reads: depth-8 floor.
// Phase A (wave = 4 points, pipelined): sp4 gathers for pt+1 and idx for
//   pt+2 in flight during pt's compute; influences in B-frag layout
//   (sentinel pad j=15), DPP row_ror normalize, feats as uint2 + v_perm;
//   one 16x16x32 bf16 MFMA per c-tile; D -> bf16 -> LDS.
// Phase B: wave wv = n-tile wv, both m-tiles; 30 x (2 ds_read_b128 +
//   1 W b128 + 2 MFMA); W B-frags straight from L2 (245 KB/block).

#define NB   16384
#define MB   16384
#define KN   32
#define CIN  64
#define COUT 128
#define KS   15
#define TP   32
#define WF_BYTES  245760u
#define FP_BYTES  (2u * MB * CIN * 2u)    // 4,194,304
#define SP4_BYTES (2u * MB * 16u)         //   524,288

typedef __attribute__((ext_vector_type(8))) short short8;
typedef __attribute__((ext_vector_type(4))) float f32x4;

// rotation-reduce step over the 16-lane DPP row: s += row_ror<n>(s)
#define ROR_ADD(s, ctrl) \
    ((s) + __int_as_float(__builtin_amdgcn_update_dpp( \
        0, __float_as_int(s), (ctrl), 0xF, 0xF, true)))

// bf16 pack (round-to-nearest, ties-away): low short = f0, high short = f1
static __device__ __forceinline__ unsigned int pack2_bf16(float f0, float f1) {
    const unsigned int a = __float_as_uint(f0) + 0x8000u;
    const unsigned int b = __float_as_uint(f1) + 0x8000u;
    return (a >> 16) | (b & 0xffff0000u);
}

static __device__ __forceinline__ unsigned int pack2_bf16_rne(float f0, float f1) {
    unsigned int a = __float_as_uint(f0);
    unsigned int b = __float_as_uint(f1);
    a += 0x7fffu + ((a >> 16) & 1u);
    b += 0x7fffu + ((b >> 16) & 1u);
    return (a >> 16) | (b & 0xffff0000u);
}

static __device__ __forceinline__ unsigned short f32_to_bf16_rne(float x) {
    unsigned int u = __float_as_uint(x);
    u += 0x7fffu + ((u >> 16) & 1u);
    return (unsigned short)(u >> 16);
}

__global__ __launch_bounds__(256)
void prep_kernel(const float* __restrict__ Wg, const float* __restrict__ feats,
                 const float* __restrict__ sp,
                 unsigned short* __restrict__ wf, unsigned int* __restrict__ fp,
                 float4* __restrict__ sp4, int full) {
    const int bid = blockIdx.x;
    if (bid < 60) {
        // W -> bf16 B-frag layout (15360 threads exactly)
        const int tid = bid * 256 + threadIdx.x;
        const int l = tid & 63;
        const int t = (tid >> 6) & 7;
        const int s = tid >> 9;
        const int n  = t * 16 + (l & 15);
        const int kb = s * 32 + (l >> 4) * 8;
        short8 o;
        #pragma unroll
        for (int i = 0; i < 8; ++i)
            o[i] = (short)f32_to_bf16_rne(Wg[(kb + i) * COUT + n]);
        *(short8*)(wf + (size_t)tid * 8) = o;
    } else if (!full) {
        return;
    } else if (bid < 60 + 128) {
        // support points -> float4 (32768 threads exactly)
        const int m = (bid - 60) * 256 + threadIdx.x;
        const float* s3 = sp + 3 * (size_t)m;
        sp4[m] = make_float4(s3[0], s3[1], s3[2], 0.0f);
    } else {
        // feats -> bf16 permuted: row m, position p=n16*4+t holds c=t*16+n16
        const unsigned int t = (unsigned int)(bid - 188) * 256u + threadIdx.x;
        if (t < 2u * MB * 32u) {          // u32 outputs: 32 per row
            const int m   = t >> 5;
            const int p2  = t & 31;       // output u32 = positions 2p2,2p2+1
            const int n16 = p2 >> 1;
            const int tt  = (p2 & 1) * 2;
            const float a = feats[(size_t)m * CIN + tt * 16 + n16];
            const float b = feats[(size_t)m * CIN + (tt + 1) * 16 + n16];
            fp[t] = pack2_bf16_rne(a, b);
        }
    }
}

template<bool PK>
__global__ __launch_bounds__(512, 4)
void kpconv_mfma(const float* __restrict__ qp,
                 const float* __restrict__ sp,
                 const float* __restrict__ feats,
                 const unsigned int* __restrict__ fpk,
                 const float4* __restrict__ sp4,
                 const int* __restrict__ nidx,
                 const float* __restrict__ kp,
                 const unsigned short* __restrict__ wfrag,
                 const float* __restrict__ bias,
                 float* __restrict__ out) {
    __shared__ __align__(16) char sF[16 * 4096];   // 65536 B -> 2 blocks/CU

    const int tid  = threadIdx.x;
    const int lane = tid & 63;
    const int wv   = tid >> 6;                 // 0..7
    const int gp_base = blockIdx.x * TP;
    const int b = gp_base >> 14;
    const float*        fbf  = feats + (size_t)b * MB * CIN;
    const unsigned int* fpb  = fpk + (size_t)b * MB * 32;       // 32 u32/row
    const float4*       sp4b = sp4 + (size_t)b * MB;
    const float*        spb  = sp + (size_t)b * MB * 3;

    const int n16  = lane & 15;     // j (influence col) / c-sub / pt-in-tile
    const int quad = lane >> 4;     // k-group selector

    // kernel point for this lane's j; j==15 pad -> sentinel far away so
    // exp(-200*d2) underflows to exactly 0
    float kxj, kyj, kzj;
    if (n16 < 15) {
        kxj = kp[3 * n16 + 0];
        kyj = kp[3 * n16 + 1];
        kzj = kp[3 * n16 + 2];
    } else {
        kxj = 1.0e4f; kyj = 1.0e4f; kzj = 1.0e4f;
    }

    // ---------------- Phase A: 4 points per wave, pipelined ----------------
    const int gp0 = gp_base + wv * 4;
    const int* ip = nidx + (size_t)gp0 * KN + quad * 8;

    int idxc[8], idxn[8];
    *(int4*)(&idxc[0]) = *(const int4*)(ip);
    *(int4*)(&idxc[4]) = *(const int4*)(ip + 4);

    // prefetch pt0 support points
    float4 s4c[8];
    if (PK) {
        #pragma unroll
        for (int i = 0; i < 8; ++i) s4c[i] = sp4b[idxc[i]];
    }
    *(int4*)(&idxn[0]) = *(const int4*)(ip + KN);
    *(int4*)(&idxn[4]) = *(const int4*)(ip + KN + 4);

    #pragma unroll
    for (int pt = 0; pt < 4; ++pt) {
        const int pl = wv * 4 + pt;
        const int gp = gp0 + pt;

        // current point's feat gathers (consumed late -> self-hiding)
        uint2 g[8];
        if (PK) {
            #pragma unroll
            for (int i = 0; i < 8; ++i)
                g[i] = *(const uint2*)(fpb + (size_t)idxc[i] * 32 + n16 * 2);
        }

        // prefetch next point's support points; idx for pt+2
        float4 s4n[8];
        if (PK && pt < 3) {
            #pragma unroll
            for (int i = 0; i < 8; ++i) s4n[i] = sp4b[idxn[i]];
        }
        int idx2[8];
        if (pt < 2) {
            const int* ip2 = ip + (pt + 2) * KN;
            *(int4*)(&idx2[0]) = *(const int4*)(ip2);
            *(int4*)(&idx2[4]) = *(const int4*)(ip2 + 4);
        }

        const float qx = qp[3 * gp + 0];
        const float qy = qp[3 * gp + 1];
        const float qz = qp[3 * gp + 2];
        const float qkx = qx + kxj, qky = qy + kyj, qkz = qz + kzj;

        float e[8];
        if (PK) {
            #pragma unroll
            for (int i = 0; i < 8; ++i) {
                const float dx = s4c[i].x - qkx;
                const float dy = s4c[i].y - qky;
                const float dz = s4c[i].z - qkz;
                const float d2 = fmaf(dx, dx, fmaf(dy, dy, dz * dz));
                e[i] = __expf(-200.0f * d2);   // 1/(2*sigma^2); j=15 -> 0
            }
        } else {
            #pragma unroll
            for (int i = 0; i < 8; ++i) {
                const float* s3 = spb + (size_t)idxc[i] * 3;
                const float dx = s3[0] - qkx;
                const float dy = s3[1] - qky;
                const float dz = s3[2] - qkz;
                const float d2 = fmaf(dx, dx, fmaf(dy, dy, dz * dz));
                e[i] = __expf(-200.0f * d2);
            }
        }

        // normalize over j = 16-lane DPP row (pure VALU)
        unsigned int iu[4];
        float en[8];
        #pragma unroll
        for (int i = 0; i < 8; ++i) {
            float s = e[i];
            s = ROR_ADD(s, 0x128);   // row_ror:8
            s = ROR_ADD(s, 0x124);   // row_ror:4
            s = ROR_ADD(s, 0x122);   // row_ror:2
            s = ROR_ADD(s, 0x121);   // row_ror:1
            en[i] = e[i] * __builtin_amdgcn_rcpf(s + 1e-6f);
        }
        #pragma unroll
        for (int ih = 0; ih < 4; ++ih)
            iu[ih] = pack2_bf16(en[2 * ih], en[2 * ih + 1]);
        const short8 ifrag = *(const short8*)iu;

        // feats A-frags: elem i = feat[idx[quad*8+i]][c=t*16+n16]
        unsigned int fu[4][4];
        if (PK) {
            #pragma unroll
            for (int ih = 0; ih < 4; ++ih) {
                const unsigned int ax = g[2 * ih].x, bx = g[2 * ih + 1].x;
                const unsigned int ay = g[2 * ih].y, by = g[2 * ih + 1].y;
                fu[0][ih] = __builtin_amdgcn_perm(bx, ax, 0x05040100u);
                fu[1][ih] = __builtin_amdgcn_perm(bx, ax, 0x07060302u);
                fu[2][ih] = __builtin_amdgcn_perm(by, ay, 0x05040100u);
                fu[3][ih] = __builtin_amdgcn_perm(by, ay, 0x07060302u);
            }
        } else {
            #pragma unroll
            for (int ih = 0; ih < 4; ++ih) {
                const float* fr0 = fbf + (size_t)idxc[2 * ih]     * CIN + n16;
                const float* fr1 = fbf + (size_t)idxc[2 * ih + 1] * CIN + n16;
                #pragma unroll
                for (int t = 0; t < 4; ++t)
                    fu[t][ih] = pack2_bf16(fr0[t * 16], fr1[t * 16]);
            }
        }

        // MFMA per c-tile t; D[c_local=quad*4+r][j=n16] -> b64 store:
        // chunk u = t*2+(quad>>1), half quad&1, row swizzle pl^(n16&7)
        #pragma unroll
        for (int t = 0; t < 4; ++t) {
            const short8 ffrag = *(const short8*)(fu[t]);
            f32x4 z = {0.f, 0.f, 0.f, 0.f};
            const f32x4 dd = __builtin_amdgcn_mfma_f32_16x16x32_bf16(ffrag, ifrag, z, 0, 0, 0);
            const unsigned int lo = pack2_bf16(dd[0], dd[1]);
            const unsigned int hi = pack2_bf16(dd[2], dd[3]);
            const int off = n16 * 4096 + (t * 2 + (quad >> 1)) * 512 +
                            ((pl ^ (n16 & 7)) * 16) + (quad & 1) * 8;
            uint2 v; v.x = lo; v.y = hi;
            *(uint2*)(sF + off) = v;                  // ds_write_b64
        }

        // rotate pipeline registers
        if (pt < 3) {
            #pragma unroll
            for (int i = 0; i < 8; ++i) {
                if (PK) s4c[i] = s4n[i];
                idxc[i] = idxn[i];
            }
            if (pt < 2) {
                #pragma unroll
                for (int i = 0; i < 8; ++i) idxn[i] = idx2[i];
            }
        }
    }
    __syncthreads();

    // --- Phase B: wave wv = n-tile; 30 x (2 ds_read_b128 + 1 W b128 + 2 MFMA) ---
    f32x4 acc0 = {0.f, 0.f, 0.f, 0.f};
    f32x4 acc1 = {0.f, 0.f, 0.f, 0.f};

    #pragma unroll
    for (int s = 0; s < 30; ++s) {
        const int j = s >> 1;
        const int u = (s & 1) * 4 + quad;
        const int off0 = j * 4096 + u * 512 + ((n16 ^ (j & 7)) * 16);
        const short8 a0 = *(const short8*)(sF + off0);
        const short8 a1 = *(const short8*)(sF + off0 + 256);   // pl += 16
        const short8 bf = *(const short8*)(wfrag + ((size_t)(s * 8 + wv) * 64 + lane) * 8);
        acc0 = __builtin_amdgcn_mfma_f32_16x16x32_bf16(a0, bf, acc0, 0, 0, 0);
        acc1 = __builtin_amdgcn_mfma_f32_16x16x32_bf16(a1, bf, acc1, 0, 0, 0);
    }

    const float bsv = bias[wv * 16 + n16];
    #pragma unroll
    for (int r = 0; r < 4; ++r) {
        const int pr = quad * 4 + r;
        out[(size_t)(gp_base + pr)      * COUT + wv * 16 + n16] = acc0[r] + bsv;
        out[(size_t)(gp_base + 16 + pr) * COUT + wv * 16 + n16] = acc1[r] + bsv;
    }
}

extern "C" void kernel_launch(void* const* d_in, const int* in_sizes, int n_in,
                              void* d_out, int out_size, void* d_ws, size_t ws_size,
                              hipStream_t stream) {
    const float* qp = (const float*)d_in[0];   // query_points   [B,N,3]
    const float* sp = (const float*)d_in[1];   // support_points [B,M,3]
    const float* ft = (const float*)d_in[2];   // support_features [B,M,C_IN]
    const int*   ni = (const int*)d_in[3];     // neighbor_idx   [B,N,K]
    const float* kp = (const float*)d_in[4];   // kernel_points  [KS,3]
    const float* wg = (const float*)d_in[5];   // weights        [KS,C_IN,C_OUT]
    const float* bs = (const float*)d_in[6];   // bias           [C_OUT]
    float* o = (float*)d_out;                  // [B,N,C_OUT] fp32

    unsigned short* wfrag = (unsigned short*)d_ws;
    unsigned int*   fpk   = (unsigned int*)((char*)d_ws + WF_BYTES);
    float4*         sp4   = (float4*)((char*)d_ws + WF_BYTES + FP_BYTES);
    const int full = (ws_size >= (size_t)(WF_BYTES + FP_BYTES + SP4_BYTES)) ? 1 : 0;

    const int prep_blocks = full ? (60 + 128 + 4096) : 60;
    hipLaunchKernelGGL(prep_kernel, dim3(prep_blocks), dim3(256), 0, stream,
                       wg, ft, sp, wfrag, fpk, sp4, full);

    if (full) {
        hipLaunchKernelGGL((kpconv_mfma<true>), dim3((2 * NB) / TP), dim3(512), 0, stream,
                           qp, sp, ft, fpk, sp4, ni, kp, wfrag, bs, o);
    } else {
        hipLaunchKernelGGL((kpconv_mfma<false>), dim3((2 * NB) / TP), dim3(512), 0, stream,
                           qp, sp, ft, fpk, sp4, ni, kp, wfrag, bs, o);
    }
}